// Round 4
// baseline (194.270 us; speedup 1.0000x reference)
//
#include <hip/hip_runtime.h>
#include <math.h>

#define N 8192
#define FIN 256
#define FOUT 64
#define ALPHA 0.2f
#define LOG2E 1.442695040888963f

typedef float f32x4 __attribute__((ext_vector_type(4)));
typedef short s16x8 __attribute__((ext_vector_type(8)));
typedef unsigned int u32x4 __attribute__((ext_vector_type(4)));

__device__ __forceinline__ unsigned pack_hi_pair(float w0, float w1) {
    return (__float_as_uint(w0) >> 16) | (__float_as_uint(w1) & 0xffff0000u);
}
__device__ __forceinline__ float trunc_bf16(float w) {
    return __uint_as_float(__float_as_uint(w) & 0xffff0000u);
}
__device__ __forceinline__ s16x8 as_s16x8(u32x4 u) {
    union { u32x4 a; s16x8 b; } c; c.a = u; return c.b;
}
__device__ __forceinline__ float wcalc(int av, float fsr, float g) {
    float e = fsr + g;
    float le = e > 0.f ? e : ALPHA * e;
    float r = __builtin_exp2f(le * LOG2E);
    return av != 0 ? r : 0.f;
}

// ---------------- Kernel 1: Wh = h@W -> fsrc/fdst + WhT hi/lo (bf16, transposed) ----
__global__ __launch_bounds__(256) void gat_prep(
    const float* __restrict__ h, const float* __restrict__ W,
    const float* __restrict__ a,
    float* __restrict__ fsrc, float* __restrict__ fdst,
    unsigned short* __restrict__ WhT_hi, unsigned short* __restrict__ WhT_lo)
{
    __shared__ float sWh[16][FOUT + 1];
    const int t = threadIdx.x;
    const int f = t & 63;
    const int wq = t >> 6;
    const int row0 = blockIdx.x * 16;
    const int rbase = row0 + wq * 4;

    float acc[4] = {0.f, 0.f, 0.f, 0.f};
    for (int k0 = 0; k0 < FIN; k0 += 4) {
        const float w0 = W[(k0 + 0) * FOUT + f];
        const float w1 = W[(k0 + 1) * FOUT + f];
        const float w2 = W[(k0 + 2) * FOUT + f];
        const float w3 = W[(k0 + 3) * FOUT + f];
#pragma unroll
        for (int rr = 0; rr < 4; ++rr) {
            const float4 hv = *reinterpret_cast<const float4*>(
                &h[(size_t)(rbase + rr) * FIN + k0]);
            acc[rr] = fmaf(hv.x, w0, acc[rr]);
            acc[rr] = fmaf(hv.y, w1, acc[rr]);
            acc[rr] = fmaf(hv.z, w2, acc[rr]);
            acc[rr] = fmaf(hv.w, w3, acc[rr]);
        }
    }
    const float as = a[f], ad = a[FOUT + f];
#pragma unroll
    for (int rr = 0; rr < 4; ++rr) {
        sWh[wq * 4 + rr][f] = acc[rr];
        float fs = acc[rr] * as, fd = acc[rr] * ad;
#pragma unroll
        for (int off = 1; off < 64; off <<= 1) {
            fs += __shfl_xor(fs, off, 64);
            fd += __shfl_xor(fd, off, 64);
        }
        if (f == 0) { fsrc[rbase + rr] = fs; fdst[rbase + rr] = fd; }
    }
    __syncthreads();
    const int ff = t >> 2;
    const int r4 = (t & 3) * 4;
    const float w0 = sWh[r4 + 0][ff], w1 = sWh[r4 + 1][ff];
    const float w2 = sWh[r4 + 2][ff], w3 = sWh[r4 + 3][ff];
    uint2 hv2, lv2;
    hv2.x = pack_hi_pair(w0, w1);
    hv2.y = pack_hi_pair(w2, w3);
    lv2.x = pack_hi_pair(w0 - trunc_bf16(w0), w1 - trunc_bf16(w1));
    lv2.y = pack_hi_pair(w2 - trunc_bf16(w2), w3 - trunc_bf16(w3));
    *reinterpret_cast<uint2*>(&WhT_hi[(size_t)ff * N + row0 + r4]) = hv2;
    *reinterpret_cast<uint2*>(&WhT_lo[(size_t)ff * N + row0 + r4]) = lv2;
}

// ---------------- Kernel 2: MFMA flash softmax-PV ----
// Issue order per k-step (vmcnt-FIFO aware): WhT loads -> wcalc -> adj prefetch
// (depth 2, static double buffer) -> MFMA. The MFMA's s_waitcnt then only needs
// to cover loads OLDER than the in-flight adj prefetch (counted vmcnt, not 0),
// so the prefetch survives the MFMA cluster.
__global__ __launch_bounds__(512, 4) void gat_main(
    const int* __restrict__ adj,
    const unsigned short* __restrict__ WhT_hi,
    const unsigned short* __restrict__ WhT_lo,
    const float* __restrict__ fsrc, const float* __restrict__ fdst,
    float* __restrict__ out)
{
    __shared__ float accbuf[8][4][64][4];  // 32 KB
    __shared__ float zbuf[8][16];
    __shared__ float Zfin[16];

    const int t = threadIdx.x;
    const int l = t & 63;
    const int w = t >> 6;
    const int row0 = blockIdx.x * 16;
    const int r = l & 15;
    const int kg8 = (l >> 4) << 3;
    const int jwbase = w * 1024;
    const float fsr = fsrc[row0 + r];
    const size_t adjrow = (size_t)(row0 + r) * N;

    f32x4 acc0 = {0.f, 0.f, 0.f, 0.f};
    f32x4 acc1 = {0.f, 0.f, 0.f, 0.f};
    f32x4 acc2 = {0.f, 0.f, 0.f, 0.f};
    f32x4 acc3 = {0.f, 0.f, 0.f, 0.f};
    float zacc = 0.f;

#define LOADK(kk, A0, A1, G0, G1)                                              \
    {                                                                          \
        const int jl_ = jwbase + (kk) * 32 + kg8;                              \
        A0 = *reinterpret_cast<const int4*>(&adj[adjrow + jl_]);               \
        A1 = *reinterpret_cast<const int4*>(&adj[adjrow + jl_ + 4]);           \
        G0 = *reinterpret_cast<const float4*>(&fdst[jl_]);                     \
        G1 = *reinterpret_cast<const float4*>(&fdst[jl_ + 4]);                 \
    }

    // STEP: WhT loads FIRST, then wcalc (VALU), then prefetch kk+2, then MFMA.
#define STEP(kk, A0, A1, G0, G1)                                               \
    {                                                                          \
        const size_t bo_ = (size_t)r * N + (jwbase + (kk) * 32 + kg8);         \
        const s16x8 bh0 = *reinterpret_cast<const s16x8*>(&WhT_hi[bo_]);       \
        const s16x8 bh1 = *reinterpret_cast<const s16x8*>(&WhT_hi[bo_ + 16*N]);\
        const s16x8 bh2 = *reinterpret_cast<const s16x8*>(&WhT_hi[bo_ + 32*N]);\
        const s16x8 bh3 = *reinterpret_cast<const s16x8*>(&WhT_hi[bo_ + 48*N]);\
        const s16x8 bl0 = *reinterpret_cast<const s16x8*>(&WhT_lo[bo_]);       \
        const s16x8 bl1 = *reinterpret_cast<const s16x8*>(&WhT_lo[bo_ + 16*N]);\
        const s16x8 bl2 = *reinterpret_cast<const s16x8*>(&WhT_lo[bo_ + 32*N]);\
        const s16x8 bl3 = *reinterpret_cast<const s16x8*>(&WhT_lo[bo_ + 48*N]);\
        const float w0 = wcalc(A0.x, fsr, G0.x), w1 = wcalc(A0.y, fsr, G0.y);  \
        const float w2 = wcalc(A0.z, fsr, G0.z), w3 = wcalc(A0.w, fsr, G0.w);  \
        const float w4 = wcalc(A1.x, fsr, G1.x), w5 = wcalc(A1.y, fsr, G1.y);  \
        const float w6 = wcalc(A1.z, fsr, G1.z), w7 = wcalc(A1.w, fsr, G1.w);  \
        zacc += (w0 + w1) + (w2 + w3) + ((w4 + w5) + (w6 + w7));               \
        u32x4 hu_, lu_;                                                        \
        hu_.x = pack_hi_pair(w0, w1); hu_.y = pack_hi_pair(w2, w3);            \
        hu_.z = pack_hi_pair(w4, w5); hu_.w = pack_hi_pair(w6, w7);            \
        lu_.x = pack_hi_pair(w0 - trunc_bf16(w0), w1 - trunc_bf16(w1));        \
        lu_.y = pack_hi_pair(w2 - trunc_bf16(w2), w3 - trunc_bf16(w3));        \
        lu_.z = pack_hi_pair(w4 - trunc_bf16(w4), w5 - trunc_bf16(w5));        \
        lu_.w = pack_hi_pair(w6 - trunc_bf16(w6), w7 - trunc_bf16(w7));        \
        const s16x8 ah = as_s16x8(hu_), al = as_s16x8(lu_);                    \
        if ((kk) + 2 < 32) { LOADK((kk) + 2, A0, A1, G0, G1); }                \
        __builtin_amdgcn_s_setprio(1);                                         \
        acc0 = __builtin_amdgcn_mfma_f32_16x16x32_bf16(ah, bh0, acc0, 0, 0, 0);\
        acc1 = __builtin_amdgcn_mfma_f32_16x16x32_bf16(ah, bh1, acc1, 0, 0, 0);\
        acc2 = __builtin_amdgcn_mfma_f32_16x16x32_bf16(ah, bh2, acc2, 0, 0, 0);\
        acc3 = __builtin_amdgcn_mfma_f32_16x16x32_bf16(ah, bh3, acc3, 0, 0, 0);\
        acc0 = __builtin_amdgcn_mfma_f32_16x16x32_bf16(ah, bl0, acc0, 0, 0, 0);\
        acc1 = __builtin_amdgcn_mfma_f32_16x16x32_bf16(ah, bl1, acc1, 0, 0, 0);\
        acc2 = __builtin_amdgcn_mfma_f32_16x16x32_bf16(ah, bl2, acc2, 0, 0, 0);\
        acc3 = __builtin_amdgcn_mfma_f32_16x16x32_bf16(ah, bl3, acc3, 0, 0, 0);\
        acc0 = __builtin_amdgcn_mfma_f32_16x16x32_bf16(al, bh0, acc0, 0, 0, 0);\
        acc1 = __builtin_amdgcn_mfma_f32_16x16x32_bf16(al, bh1, acc1, 0, 0, 0);\
        acc2 = __builtin_amdgcn_mfma_f32_16x16x32_bf16(al, bh2, acc2, 0, 0, 0);\
        acc3 = __builtin_amdgcn_mfma_f32_16x16x32_bf16(al, bh3, acc3, 0, 0, 0);\
        __builtin_amdgcn_s_setprio(0);                                         \
    }

    int4 a0A, a1A; float4 g0A, g1A;
    int4 a0B, a1B; float4 g0B, g1B;
    LOADK(0, a0A, a1A, g0A, g1A);
    LOADK(1, a0B, a1B, g0B, g1B);
    for (int kk = 0; kk < 32; kk += 2) {
        STEP(kk,     a0A, a1A, g0A, g1A);
        STEP(kk + 1, a0B, a1B, g0B, g1B);
    }
#undef LOADK
#undef STEP

    // ---- cross-wave reduction ----
    zacc += __shfl_xor(zacc, 16, 64);
    zacc += __shfl_xor(zacc, 32, 64);
    if (l < 16) zbuf[w][l] = zacc;
    *reinterpret_cast<f32x4*>(&accbuf[w][0][l][0]) = acc0;
    *reinterpret_cast<f32x4*>(&accbuf[w][1][l][0]) = acc1;
    *reinterpret_cast<f32x4*>(&accbuf[w][2][l][0]) = acc2;
    *reinterpret_cast<f32x4*>(&accbuf[w][3][l][0]) = acc3;
    __syncthreads();
    if (t < 16) {
        float z = 0.f;
#pragma unroll
        for (int w2 = 0; w2 < 8; ++w2) z += zbuf[w2][t];
        Zfin[t] = z;
    }
    __syncthreads();

    // D layout (verified): col = lane&15, row = (lane>>4)*4 + reg
#pragma unroll
    for (int e0 = 0; e0 < 2; ++e0) {
        const int e = t + e0 * 512;
        const int rr = e >> 6, f2 = e & 63;
        const int c = f2 >> 4;
        const int ln = (f2 & 15) | ((rr >> 2) << 4);
        const int rg = rr & 3;
        float s = 0.f;
#pragma unroll
        for (int w2 = 0; w2 < 8; ++w2) s += accbuf[w2][c][ln][rg];
        const float hp = s / Zfin[rr];
        out[(size_t)(row0 + rr) * FOUT + f2] = hp > 0.f ? hp : expm1f(hp);
    }
}

extern "C" void kernel_launch(void* const* d_in, const int* in_sizes, int n_in,
                              void* d_out, int out_size, void* d_ws, size_t ws_size,
                              hipStream_t stream) {
    const float* h   = (const float*)d_in[0];
    const int*   adj = (const int*)d_in[1];
    const float* W   = (const float*)d_in[2];
    const float* a   = (const float*)d_in[3];
    float* out = (float*)d_out;

    float* ws = (float*)d_ws;
    float* fsrc = ws;
    float* fdst = fsrc + N;
    unsigned short* WhT_hi = (unsigned short*)(fdst + N);
    unsigned short* WhT_lo = WhT_hi + (size_t)FOUT * N;

    gat_prep<<<dim3(N / 16), dim3(256), 0, stream>>>(
        h, W, a, fsrc, fdst, WhT_hi, WhT_lo);
    gat_main<<<dim3(N / 16), dim3(512), 0, stream>>>(
        adj, WhT_hi, WhT_lo, fsrc, fdst, out);
}

// Round 5
// 115.491 us; speedup vs baseline: 1.6821x; 1.6821x over previous
//
#include <hip/hip_runtime.h>
#include <math.h>

#define N 8192
#define FIN 256
#define FOUT 64
#define ALPHA 0.2f
#define LOG2E 1.442695040888963f

#define JT 128               // j-tile columns
#define NTILE (N / JT)       // 64
#define PITCHB 272           // bytes per LDS tile row (136 bf16) -> 2-way banks, 16B aligned
#define OFF_BH 0             // WhT_hi tile [64][PITCHB]
#define OFF_BL (64 * PITCHB)
#define OFF_AH (2 * 64 * PITCHB)            // w_hi tile [16][PITCHB]
#define OFF_AL (2 * 64 * PITCHB + 16 * PITCHB)
#define SMEM_BYTES (2 * 64 * PITCHB + 2 * 16 * PITCHB)   // 43520

typedef float f32x4 __attribute__((ext_vector_type(4)));
typedef short s16x8 __attribute__((ext_vector_type(8)));

__device__ __forceinline__ unsigned pack_hi_pair(float w0, float w1) {
    return (__float_as_uint(w0) >> 16) | (__float_as_uint(w1) & 0xffff0000u);
}
__device__ __forceinline__ float trunc_bf16(float w) {
    return __uint_as_float(__float_as_uint(w) & 0xffff0000u);
}
__device__ __forceinline__ float wcalc(int av, float fsr, float g) {
    float e = fsr + g;
    float le = e > 0.f ? e : ALPHA * e;
    float r = __builtin_exp2f(le * LOG2E);
    return av != 0 ? r : 0.f;
}

// ---------------- Kernel 1: Wh = h@W -> fsrc/fdst + WhT hi/lo (bf16, transposed) ----
__global__ __launch_bounds__(256) void gat_prep(
    const float* __restrict__ h, const float* __restrict__ W,
    const float* __restrict__ a,
    float* __restrict__ fsrc, float* __restrict__ fdst,
    unsigned short* __restrict__ WhT_hi, unsigned short* __restrict__ WhT_lo)
{
    __shared__ float sWh[16][FOUT + 1];
    const int t = threadIdx.x;
    const int f = t & 63;
    const int wq = t >> 6;
    const int row0 = blockIdx.x * 16;
    const int rbase = row0 + wq * 4;

    float acc[4] = {0.f, 0.f, 0.f, 0.f};
    for (int k0 = 0; k0 < FIN; k0 += 4) {
        const float w0 = W[(k0 + 0) * FOUT + f];
        const float w1 = W[(k0 + 1) * FOUT + f];
        const float w2 = W[(k0 + 2) * FOUT + f];
        const float w3 = W[(k0 + 3) * FOUT + f];
#pragma unroll
        for (int rr = 0; rr < 4; ++rr) {
            const float4 hv = *reinterpret_cast<const float4*>(
                &h[(size_t)(rbase + rr) * FIN + k0]);
            acc[rr] = fmaf(hv.x, w0, acc[rr]);
            acc[rr] = fmaf(hv.y, w1, acc[rr]);
            acc[rr] = fmaf(hv.z, w2, acc[rr]);
            acc[rr] = fmaf(hv.w, w3, acc[rr]);
        }
    }
    const float as = a[f], ad = a[FOUT + f];
#pragma unroll
    for (int rr = 0; rr < 4; ++rr) {
        sWh[wq * 4 + rr][f] = acc[rr];
        float fs = acc[rr] * as, fd = acc[rr] * ad;
#pragma unroll
        for (int off = 1; off < 64; off <<= 1) {
            fs += __shfl_xor(fs, off, 64);
            fd += __shfl_xor(fd, off, 64);
        }
        if (f == 0) { fsrc[rbase + rr] = fs; fdst[rbase + rr] = fd; }
    }
    __syncthreads();
    const int ff = t >> 2;
    const int r4 = (t & 3) * 4;
    const float w0 = sWh[r4 + 0][ff], w1 = sWh[r4 + 1][ff];
    const float w2 = sWh[r4 + 2][ff], w3 = sWh[r4 + 3][ff];
    uint2 hv2, lv2;
    hv2.x = pack_hi_pair(w0, w1);
    hv2.y = pack_hi_pair(w2, w3);
    lv2.x = pack_hi_pair(w0 - trunc_bf16(w0), w1 - trunc_bf16(w1));
    lv2.y = pack_hi_pair(w2 - trunc_bf16(w2), w3 - trunc_bf16(w3));
    *reinterpret_cast<uint2*>(&WhT_hi[(size_t)ff * N + row0 + r4]) = hv2;
    *reinterpret_cast<uint2*>(&WhT_lo[(size_t)ff * N + row0 + r4]) = lv2;
}

// ---------------- Kernel 2: LDS-tiled MFMA flash softmax-PV ----
// No scattered global loads in the hot loop: adj read contiguously per row,
// WhT staged via coalesced global->reg->LDS (T14 split). Fragments come from
// LDS (pitch-padded, ~2-way banks). 8 waves: ftile = w&3, k-parity = w>>2.
__global__ __launch_bounds__(512, 6) void gat_main(
    const int* __restrict__ adj,
    const unsigned short* __restrict__ WhT_hi,
    const unsigned short* __restrict__ WhT_lo,
    const float* __restrict__ fsrc, const float* __restrict__ fdst,
    float* __restrict__ out)
{
    __shared__ __align__(16) char smem[SMEM_BYTES];
    __shared__ float zbuf[16];

    const int t = threadIdx.x;
    const int l = t & 63;
    const int w = t >> 6;
    const int row0 = blockIdx.x * 16;

    // --- staging maps ---
    const int srow = t >> 5;               // 0..15 (adj/w row)
    const int sc0 = (t & 31) * 4;          // col within tile
    const int bf = t >> 3;                 // 0..63 (WhT f-row)
    const int bg = t & 7;                  // granule id
    const int G1 = ((bg + bf) & 7);        // rotated granule -> 2-way write banks
    const int G2 = G1 + 8;
    const float fsr = fsrc[row0 + srow];
    const size_t adjrow = (size_t)(row0 + srow) * N;
    const size_t bfrow = (size_t)bf * N;

    // --- MFMA maps ---
    const int ft = w & 3;
    const int p = w >> 2;
    const int r16 = l & 15;
    const int kg8 = (l >> 4) << 3;
    char* ahp = smem + OFF_AH + r16 * PITCHB;
    char* alp = smem + OFF_AL + r16 * PITCHB;
    char* bhp = smem + OFF_BH + (ft * 16 + r16) * PITCHB;
    char* blp = smem + OFF_BL + (ft * 16 + r16) * PITCHB;

    f32x4 acc = {0.f, 0.f, 0.f, 0.f};
    float zacc = 0.f;

    int4 adjreg; float4 gdst;
    int4 whh0, whh1, whl0, whl1;

#define LOADG(tile)                                                            \
    {                                                                          \
        const int j0_ = (tile) * JT;                                           \
        adjreg = *reinterpret_cast<const int4*>(&adj[adjrow + j0_ + sc0]);     \
        gdst = *reinterpret_cast<const float4*>(&fdst[j0_ + sc0]);             \
        whh0 = *reinterpret_cast<const int4*>(&WhT_hi[bfrow + j0_ + G1 * 8]);  \
        whh1 = *reinterpret_cast<const int4*>(&WhT_hi[bfrow + j0_ + G2 * 8]);  \
        whl0 = *reinterpret_cast<const int4*>(&WhT_lo[bfrow + j0_ + G1 * 8]);  \
        whl1 = *reinterpret_cast<const int4*>(&WhT_lo[bfrow + j0_ + G2 * 8]);  \
    }

    LOADG(0);
    for (int tt = 0; tt < NTILE; ++tt) {
        // ---- stage into LDS (uses G-regs of tile tt) ----
        *reinterpret_cast<int4*>(smem + OFF_BH + bf * PITCHB + G1 * 16) = whh0;
        *reinterpret_cast<int4*>(smem + OFF_BH + bf * PITCHB + G2 * 16) = whh1;
        *reinterpret_cast<int4*>(smem + OFF_BL + bf * PITCHB + G1 * 16) = whl0;
        *reinterpret_cast<int4*>(smem + OFF_BL + bf * PITCHB + G2 * 16) = whl1;
        {
            const float w0 = wcalc(adjreg.x, fsr, gdst.x);
            const float w1 = wcalc(adjreg.y, fsr, gdst.y);
            const float w2 = wcalc(adjreg.z, fsr, gdst.z);
            const float w3 = wcalc(adjreg.w, fsr, gdst.w);
            zacc += (w0 + w1) + (w2 + w3);
            uint2 hi, lo;
            hi.x = pack_hi_pair(w0, w1);
            hi.y = pack_hi_pair(w2, w3);
            lo.x = pack_hi_pair(w0 - trunc_bf16(w0), w1 - trunc_bf16(w1));
            lo.y = pack_hi_pair(w2 - trunc_bf16(w2), w3 - trunc_bf16(w3));
            *reinterpret_cast<uint2*>(smem + OFF_AH + srow * PITCHB + sc0 * 2) = hi;
            *reinterpret_cast<uint2*>(smem + OFF_AL + srow * PITCHB + sc0 * 2) = lo;
        }
        // ---- issue next tile's global loads (latency hides under MFMA) ----
        if (tt + 1 < NTILE) LOADG(tt + 1);
        __syncthreads();
        // ---- MFMA phase: frags from LDS ----
        __builtin_amdgcn_s_setprio(1);
#pragma unroll
        for (int ks = 0; ks < 2; ++ks) {
            const int jl = (p * 64 + ks * 32 + kg8) * 2;   // byte offset
            const s16x8 ah = *reinterpret_cast<const s16x8*>(ahp + jl);
            const s16x8 al = *reinterpret_cast<const s16x8*>(alp + jl);
            const s16x8 bh = *reinterpret_cast<const s16x8*>(bhp + jl);
            const s16x8 bl = *reinterpret_cast<const s16x8*>(blp + jl);
            acc = __builtin_amdgcn_mfma_f32_16x16x32_bf16(ah, bh, acc, 0, 0, 0);
            acc = __builtin_amdgcn_mfma_f32_16x16x32_bf16(ah, bl, acc, 0, 0, 0);
            acc = __builtin_amdgcn_mfma_f32_16x16x32_bf16(al, bh, acc, 0, 0, 0);
        }
        __builtin_amdgcn_s_setprio(0);
        __syncthreads();
    }
#undef LOADG

    // ---- Z reduction: each row's 32 threads live in one wave half ----
    {
        float z = zacc;
#pragma unroll
        for (int off = 1; off < 32; off <<= 1) z += __shfl_xor(z, off, 64);
        if ((l & 31) == 0) zbuf[srow] = z;
    }

    // ---- cross-parity D reduction + epilogue (accbuf aliases tile LDS) ----
    *reinterpret_cast<f32x4*>(smem + w * 1024 + l * 16) = acc;
    __syncthreads();
#pragma unroll
    for (int e0 = 0; e0 < 2; ++e0) {
        const int e = t + e0 * 512;
        const int rr = e >> 6, f2 = e & 63;
        const int ft2 = f2 >> 4, n = f2 & 15;
        const int ln = n | ((rr >> 2) << 4);
        const int rg = rr & 3;
        const float s =
            *reinterpret_cast<const float*>(smem + ft2 * 1024 + ln * 16 + rg * 4) +
            *reinterpret_cast<const float*>(smem + (ft2 + 4) * 1024 + ln * 16 + rg * 4);
        const float hp = s / zbuf[rr];
        out[(size_t)(row0 + rr) * FOUT + f2] = hp > 0.f ? hp : expm1f(hp);
    }
}

extern "C" void kernel_launch(void* const* d_in, const int* in_sizes, int n_in,
                              void* d_out, int out_size, void* d_ws, size_t ws_size,
                              hipStream_t stream) {
    const float* h   = (const float*)d_in[0];
    const int*   adj = (const int*)d_in[1];
    const float* W   = (const float*)d_in[2];
    const float* a   = (const float*)d_in[3];
    float* out = (float*)d_out;

    float* ws = (float*)d_ws;
    float* fsrc = ws;
    float* fdst = fsrc + N;
    unsigned short* WhT_hi = (unsigned short*)(fdst + N);
    unsigned short* WhT_lo = WhT_hi + (size_t)FOUT * N;

    gat_prep<<<dim3(N / 16), dim3(256), 0, stream>>>(
        h, W, a, fsrc, fdst, WhT_hi, WhT_lo);
    gat_main<<<dim3(N / 16), dim3(512), 0, stream>>>(
        adj, WhT_hi, WhT_lo, fsrc, fdst, out);
}

// Round 6
// 97.202 us; speedup vs baseline: 1.9986x; 1.1882x over previous
//
#include <hip/hip_runtime.h>
#include <math.h>

#define N 8192
#define FIN 256
#define FOUT 64
#define ALPHA 0.2f
#define LOG2E 1.442695040888963f

#define JT 256                    // j-tile columns
#define NTILE (N / JT)            // 32
#define ROWPITCH 512              // bytes per LDS tile row (256 f16)
#define OFF_B 0                   // B tile [64][ROWPITCH]
#define OFF_A (64 * ROWPITCH)     // A tile [16][ROWPITCH]
#define SMEM_BYTES (OFF_A + 16 * ROWPITCH)   // 40960

typedef float f32x4 __attribute__((ext_vector_type(4)));
typedef _Float16 f16x8 __attribute__((ext_vector_type(8)));

__device__ __forceinline__ unsigned pack_f16(float a, float b) {
    union { _Float16 h; unsigned short u; } ca, cb;
    ca.h = (_Float16)a; cb.h = (_Float16)b;      // v_cvt_f16_f32, RNE
    return (unsigned)ca.u | ((unsigned)cb.u << 16);
}
// w' = exp(leaky(e)) * 2^-4  (scale cancels in softmax ratio; keeps f16 in range)
__device__ __forceinline__ float wcalc(int av, float fsr, float g) {
    float e = fsr + g;
    float le = e > 0.f ? e : ALPHA * e;
    float r = __builtin_exp2f(fmaf(le, LOG2E, -4.0f));
    return av != 0 ? r : 0.f;
}

// ---------------- Kernel 1: Wh = h@W -> fsrc/fdst + WhT (f16, transposed) ----
__global__ __launch_bounds__(256) void gat_prep(
    const float* __restrict__ h, const float* __restrict__ W,
    const float* __restrict__ a,
    float* __restrict__ fsrc, float* __restrict__ fdst,
    unsigned short* __restrict__ WhT)
{
    __shared__ float sWh[16][FOUT + 1];
    const int t = threadIdx.x;
    const int f = t & 63;
    const int wq = t >> 6;
    const int row0 = blockIdx.x * 16;
    const int rbase = row0 + wq * 4;

    float acc[4] = {0.f, 0.f, 0.f, 0.f};
    for (int k0 = 0; k0 < FIN; k0 += 4) {
        const float w0 = W[(k0 + 0) * FOUT + f];
        const float w1 = W[(k0 + 1) * FOUT + f];
        const float w2 = W[(k0 + 2) * FOUT + f];
        const float w3 = W[(k0 + 3) * FOUT + f];
#pragma unroll
        for (int rr = 0; rr < 4; ++rr) {
            const float4 hv = *reinterpret_cast<const float4*>(
                &h[(size_t)(rbase + rr) * FIN + k0]);
            acc[rr] = fmaf(hv.x, w0, acc[rr]);
            acc[rr] = fmaf(hv.y, w1, acc[rr]);
            acc[rr] = fmaf(hv.z, w2, acc[rr]);
            acc[rr] = fmaf(hv.w, w3, acc[rr]);
        }
    }
    const float as = a[f], ad = a[FOUT + f];
#pragma unroll
    for (int rr = 0; rr < 4; ++rr) {
        sWh[wq * 4 + rr][f] = acc[rr];
        float fs = acc[rr] * as, fd = acc[rr] * ad;
#pragma unroll
        for (int off = 1; off < 64; off <<= 1) {
            fs += __shfl_xor(fs, off, 64);
            fd += __shfl_xor(fd, off, 64);
        }
        if (f == 0) { fsrc[rbase + rr] = fs; fdst[rbase + rr] = fd; }
    }
    __syncthreads();
    const int ff = t >> 2;
    const int r4 = (t & 3) * 4;
    uint2 v;
    v.x = pack_f16(sWh[r4 + 0][ff], sWh[r4 + 1][ff]);
    v.y = pack_f16(sWh[r4 + 2][ff], sWh[r4 + 3][ff]);
    *reinterpret_cast<uint2*>(&WhT[(size_t)ff * N + row0 + r4]) = v;
}

// ---------------- Kernel 2: LDS-tiled f16-MFMA flash softmax-PV ----
// JT=256, depth-2 static register prefetch, XOR-swizzled LDS tiles.
// 8 waves: ft = w&3 (16 f-rows), p = w>>2 (k-half); 4 MFMA/tile/wave.
struct Regs { int4 a0, a1; float4 g0, g1; int4 b0, b1, b2, b3; };

__global__ __launch_bounds__(512, 4) void gat_main(
    const int* __restrict__ adj,
    const unsigned short* __restrict__ WhT,
    const float* __restrict__ fsrc, const float* __restrict__ fdst,
    float* __restrict__ out)
{
    __shared__ __align__(16) char smem[SMEM_BYTES];
    __shared__ float zbuf[16];

    const int t = threadIdx.x;
    const int l = t & 63;
    const int w = t >> 6;
    const int row0 = blockIdx.x * 16;

    // --- staging maps ---
    const int srow = t >> 5;               // 0..15 adj/w row
    const int sc8 = (t & 31) * 8;          // col (elements)
    const int bf = t >> 3;                 // 0..63 WhT f-row
    const int bg = t & 7;                  // base granule
    const float fsr = fsrc[row0 + srow];
    const size_t adjrow = (size_t)(row0 + srow) * N;
    const size_t bfrow = (size_t)bf * N;

    const int aswz = (srow & 7) << 4;
    const int bswz = (bf & 7) << 4;
    char* aw = smem + OFF_A + srow * ROWPITCH + (((t & 31) * 16) ^ aswz);
    char* bw0 = smem + OFF_B + bf * ROWPITCH + (((bg + 0) * 16) ^ bswz);
    char* bw1 = smem + OFF_B + bf * ROWPITCH + (((bg + 8) * 16) ^ bswz);
    char* bw2 = smem + OFF_B + bf * ROWPITCH + (((bg + 16) * 16) ^ bswz);
    char* bw3 = smem + OFF_B + bf * ROWPITCH + (((bg + 24) * 16) ^ bswz);

    // --- MFMA maps ---
    const int ft = w & 3;
    const int p = w >> 2;
    const int r16 = l & 15;
    const int kg8 = (l >> 4) << 3;
    const int fswz = (r16 & 7) << 4;       // brow&7 == r16&7
    const char* ar = smem + OFF_A + r16 * ROWPITCH;
    const char* br = smem + OFF_B + (ft * 16 + r16) * ROWPITCH;

    f32x4 acc = {0.f, 0.f, 0.f, 0.f};
    float zacc = 0.f;
    Regs RA, RB;

#define LOADG(tile, S)                                                         \
    {                                                                          \
        const int j0_ = (tile) * JT;                                           \
        S.a0 = *reinterpret_cast<const int4*>(&adj[adjrow + j0_ + sc8]);       \
        S.a1 = *reinterpret_cast<const int4*>(&adj[adjrow + j0_ + sc8 + 4]);   \
        S.g0 = *reinterpret_cast<const float4*>(&fdst[j0_ + sc8]);             \
        S.g1 = *reinterpret_cast<const float4*>(&fdst[j0_ + sc8 + 4]);         \
        S.b0 = *reinterpret_cast<const int4*>(&WhT[bfrow + j0_ + (bg+0)*8]);   \
        S.b1 = *reinterpret_cast<const int4*>(&WhT[bfrow + j0_ + (bg+8)*8]);   \
        S.b2 = *reinterpret_cast<const int4*>(&WhT[bfrow + j0_ + (bg+16)*8]);  \
        S.b3 = *reinterpret_cast<const int4*>(&WhT[bfrow + j0_ + (bg+24)*8]);  \
    }

#define STAGE(S)                                                               \
    {                                                                          \
        *reinterpret_cast<int4*>(bw0) = S.b0;                                  \
        *reinterpret_cast<int4*>(bw1) = S.b1;                                  \
        *reinterpret_cast<int4*>(bw2) = S.b2;                                  \
        *reinterpret_cast<int4*>(bw3) = S.b3;                                  \
        const float w0 = wcalc(S.a0.x, fsr, S.g0.x);                           \
        const float w1 = wcalc(S.a0.y, fsr, S.g0.y);                           \
        const float w2 = wcalc(S.a0.z, fsr, S.g0.z);                           \
        const float w3 = wcalc(S.a0.w, fsr, S.g0.w);                           \
        const float w4 = wcalc(S.a1.x, fsr, S.g1.x);                           \
        const float w5 = wcalc(S.a1.y, fsr, S.g1.y);                           \
        const float w6 = wcalc(S.a1.z, fsr, S.g1.z);                           \
        const float w7 = wcalc(S.a1.w, fsr, S.g1.w);                           \
        zacc += (w0 + w1) + (w2 + w3) + ((w4 + w5) + (w6 + w7));               \
        uint4 pk;                                                              \
        pk.x = pack_f16(w0, w1); pk.y = pack_f16(w2, w3);                      \
        pk.z = pack_f16(w4, w5); pk.w = pack_f16(w6, w7);                      \
        *reinterpret_cast<uint4*>(aw) = pk;                                    \
    }

#define MFMA_PHASE                                                             \
    {                                                                          \
        __builtin_amdgcn_s_setprio(1);                                         \
        _Pragma("unroll")                                                      \
        for (int ks = 0; ks < 4; ++ks) {                                       \
            const int cb = (p * 128 + ks * 32 + kg8) * 2;                      \
            const f16x8 af = *reinterpret_cast<const f16x8*>(ar + (cb ^ fswz));\
            const f16x8 bfv = *reinterpret_cast<const f16x8*>(br + (cb ^ fswz));\
            acc = __builtin_amdgcn_mfma_f32_16x16x32_f16(af, bfv, acc, 0, 0, 0);\
        }                                                                      \
        __builtin_amdgcn_s_setprio(0);                                         \
    }

    LOADG(0, RA);
    LOADG(1, RB);
    for (int tt = 0; tt < NTILE; tt += 2) {
        STAGE(RA);
        if (tt + 2 < NTILE) LOADG(tt + 2, RA);
        __syncthreads();
        MFMA_PHASE;
        __syncthreads();
        STAGE(RB);
        if (tt + 3 < NTILE) LOADG(tt + 3, RB);
        __syncthreads();
        MFMA_PHASE;
        __syncthreads();
    }
#undef LOADG
#undef STAGE
#undef MFMA_PHASE

    // ---- Z reduction (each row's 32 threads share a wave half) ----
    {
        float z = zacc;
#pragma unroll
        for (int off = 1; off < 32; off <<= 1) z += __shfl_xor(z, off, 64);
        if ((l & 31) == 0) zbuf[srow] = z;
    }

    // ---- cross-parity D reduction + epilogue (aliases tile LDS) ----
    *reinterpret_cast<f32x4*>(smem + w * 1024 + l * 16) = acc;
    __syncthreads();
#pragma unroll
    for (int e0 = 0; e0 < 2; ++e0) {
        const int e = t + e0 * 512;
        const int rr = e >> 6, f2 = e & 63;
        const int ft2 = f2 >> 4, n = f2 & 15;
        const int ln = n | ((rr >> 2) << 4);
        const int rg = rr & 3;
        const float s =
            *reinterpret_cast<const float*>(smem + ft2 * 1024 + ln * 16 + rg * 4) +
            *reinterpret_cast<const float*>(smem + (ft2 + 4) * 1024 + ln * 16 + rg * 4);
        const float hp = s / zbuf[rr];
        out[(size_t)(row0 + rr) * FOUT + f2] = hp > 0.f ? hp : expm1f(hp);
    }
}

extern "C" void kernel_launch(void* const* d_in, const int* in_sizes, int n_in,
                              void* d_out, int out_size, void* d_ws, size_t ws_size,
                              hipStream_t stream) {
    const float* h   = (const float*)d_in[0];
    const int*   adj = (const int*)d_in[1];
    const float* W   = (const float*)d_in[2];
    const float* a   = (const float*)d_in[3];
    float* out = (float*)d_out;

    float* ws = (float*)d_ws;
    float* fsrc = ws;
    float* fdst = fsrc + N;
    unsigned short* WhT = (unsigned short*)(fdst + N);   // FOUT*N f16 = 1 MB

    gat_prep<<<dim3(N / 16), dim3(256), 0, stream>>>(h, W, a, fsrc, fdst, WhT);
    gat_main<<<dim3(N / 16), dim3(512), 0, stream>>>(adj, WhT, fsrc, fdst, out);
}

// Round 7
// 92.748 us; speedup vs baseline: 2.0946x; 1.0480x over previous
//
#include <hip/hip_runtime.h>
#include <math.h>

#define N 8192
#define FIN 256
#define FOUT 64
#define ALPHA 0.2f
#define LOG2E 1.442695040888963f

#define JT 256                    // j-tile columns
#define NTILE (N / JT)            // 32
#define ROWPITCH 512              // bytes per LDS tile row (256 f16)
#define OFF_B 0                   // B tile [64][ROWPITCH]
#define OFF_A (64 * ROWPITCH)     // A tile [16][ROWPITCH]
#define BUFB (OFF_A + 16 * ROWPITCH)      // 40960 per buffer
#define SMEM_BYTES (2 * BUFB)             // 81920 -> exactly 2 blocks/CU

typedef float f32x4 __attribute__((ext_vector_type(4)));
typedef _Float16 f16x8 __attribute__((ext_vector_type(8)));

__device__ __forceinline__ unsigned pack_f16(float a, float b) {
    union { _Float16 h; unsigned short u; } ca, cb;
    ca.h = (_Float16)a; cb.h = (_Float16)b;      // v_cvt_f16_f32, RNE
    return (unsigned)ca.u | ((unsigned)cb.u << 16);
}
// w' = exp(leaky(e)) * 2^-4  (scale cancels in softmax ratio; keeps f16 in range)
__device__ __forceinline__ float wcalc(int av, float fsr, float g) {
    float e = fsr + g;
    float le = e > 0.f ? e : ALPHA * e;
    float r = __builtin_exp2f(fmaf(le, LOG2E, -4.0f));
    return av != 0 ? r : 0.f;
}

// ---------------- Kernel 1: Wh = h@W -> fsrc/fdst + WhT (f16, transposed) ----
__global__ __launch_bounds__(256) void gat_prep(
    const float* __restrict__ h, const float* __restrict__ W,
    const float* __restrict__ a,
    float* __restrict__ fsrc, float* __restrict__ fdst,
    unsigned short* __restrict__ WhT)
{
    __shared__ float sWh[16][FOUT + 1];
    const int t = threadIdx.x;
    const int f = t & 63;
    const int wq = t >> 6;
    const int row0 = blockIdx.x * 16;
    const int rbase = row0 + wq * 4;

    float acc[4] = {0.f, 0.f, 0.f, 0.f};
    for (int k0 = 0; k0 < FIN; k0 += 4) {
        const float w0 = W[(k0 + 0) * FOUT + f];
        const float w1 = W[(k0 + 1) * FOUT + f];
        const float w2 = W[(k0 + 2) * FOUT + f];
        const float w3 = W[(k0 + 3) * FOUT + f];
#pragma unroll
        for (int rr = 0; rr < 4; ++rr) {
            const float4 hv = *reinterpret_cast<const float4*>(
                &h[(size_t)(rbase + rr) * FIN + k0]);
            acc[rr] = fmaf(hv.x, w0, acc[rr]);
            acc[rr] = fmaf(hv.y, w1, acc[rr]);
            acc[rr] = fmaf(hv.z, w2, acc[rr]);
            acc[rr] = fmaf(hv.w, w3, acc[rr]);
        }
    }
    const float as = a[f], ad = a[FOUT + f];
#pragma unroll
    for (int rr = 0; rr < 4; ++rr) {
        sWh[wq * 4 + rr][f] = acc[rr];
        float fs = acc[rr] * as, fd = acc[rr] * ad;
#pragma unroll
        for (int off = 1; off < 64; off <<= 1) {
            fs += __shfl_xor(fs, off, 64);
            fd += __shfl_xor(fd, off, 64);
        }
        if (f == 0) { fsrc[rbase + rr] = fs; fdst[rbase + rr] = fd; }
    }
    __syncthreads();
    const int ff = t >> 2;
    const int r4 = (t & 3) * 4;
    uint2 v;
    v.x = pack_f16(sWh[r4 + 0][ff], sWh[r4 + 1][ff]);
    v.y = pack_f16(sWh[r4 + 2][ff], sWh[r4 + 3][ff]);
    *reinterpret_cast<uint2*>(&WhT[(size_t)ff * N + row0 + r4]) = v;
}

// ---------------- Kernel 2: dbuf LDS f16-MFMA flash softmax-PV ----
// Raw s_barrier + lgkmcnt(0)-only waits: vmcnt is NEVER drained in the main
// loop, so the depth-2 register prefetch survives the barriers (T3/T4).
// Ping-pong LDS buffers, 1 barrier/tile, loop unrolled x2 (static indices).
struct Regs { int4 a0, a1; float4 g0, g1; int4 b0, b1, b2, b3; };

__global__ __launch_bounds__(512, 4) void gat_main(
    const int* __restrict__ adj,
    const unsigned short* __restrict__ WhT,
    const float* __restrict__ fsrc, const float* __restrict__ fdst,
    float* __restrict__ out)
{
    __shared__ __align__(16) char smem[SMEM_BYTES];

    const int t = threadIdx.x;
    const int l = t & 63;
    const int w = t >> 6;
    const int row0 = blockIdx.x * 16;

    // --- staging maps ---
    const int srow = t >> 5;               // 0..15 adj/w row
    const int sc8 = (t & 31) * 8;          // col (elements)
    const int bf = t >> 3;                 // 0..63 WhT f-row
    const int bg = t & 7;                  // base granule
    const float fsr = fsrc[row0 + srow];
    const size_t adjrow = (size_t)(row0 + srow) * N;
    const size_t bfrow = (size_t)bf * N;

    const int aswz = (srow & 7) << 4;
    const int bswz = (bf & 7) << 4;
    const int awo  = OFF_A + srow * ROWPITCH + (((t & 31) * 16) ^ aswz);
    const int bwo0 = OFF_B + bf * ROWPITCH + (((bg + 0) * 16) ^ bswz);
    const int bwo1 = OFF_B + bf * ROWPITCH + (((bg + 8) * 16) ^ bswz);
    const int bwo2 = OFF_B + bf * ROWPITCH + (((bg + 16) * 16) ^ bswz);
    const int bwo3 = OFF_B + bf * ROWPITCH + (((bg + 24) * 16) ^ bswz);

    // --- MFMA maps ---
    const int ft = w & 3;
    const int p = w >> 2;
    const int r16 = l & 15;
    const int kg8 = (l >> 4) << 3;
    const int fswz = (r16 & 7) << 4;       // row&7 == r16&7 for both tiles
    const int aro = OFF_A + r16 * ROWPITCH;
    const int bro = OFF_B + (ft * 16 + r16) * ROWPITCH;

    f32x4 acc = {0.f, 0.f, 0.f, 0.f};
    float zacc = 0.f;
    Regs RA, RB;

#define BAR                                                                    \
    {                                                                          \
        asm volatile("s_waitcnt lgkmcnt(0)" ::: "memory");                     \
        __builtin_amdgcn_s_barrier();                                          \
    }

#define LOADG(tile, S)                                                         \
    {                                                                          \
        const int j0_ = (tile) * JT;                                           \
        S.a0 = *reinterpret_cast<const int4*>(&adj[adjrow + j0_ + sc8]);       \
        S.a1 = *reinterpret_cast<const int4*>(&adj[adjrow + j0_ + sc8 + 4]);   \
        S.g0 = *reinterpret_cast<const float4*>(&fdst[j0_ + sc8]);             \
        S.g1 = *reinterpret_cast<const float4*>(&fdst[j0_ + sc8 + 4]);         \
        S.b0 = *reinterpret_cast<const int4*>(&WhT[bfrow + j0_ + (bg+0)*8]);   \
        S.b1 = *reinterpret_cast<const int4*>(&WhT[bfrow + j0_ + (bg+8)*8]);   \
        S.b2 = *reinterpret_cast<const int4*>(&WhT[bfrow + j0_ + (bg+16)*8]);  \
        S.b3 = *reinterpret_cast<const int4*>(&WhT[bfrow + j0_ + (bg+24)*8]);  \
    }

#define STAGE(S, BUF)                                                          \
    {                                                                          \
        char* bs_ = smem + (BUF) * BUFB;                                       \
        *reinterpret_cast<int4*>(bs_ + bwo0) = S.b0;                           \
        *reinterpret_cast<int4*>(bs_ + bwo1) = S.b1;                           \
        *reinterpret_cast<int4*>(bs_ + bwo2) = S.b2;                           \
        *reinterpret_cast<int4*>(bs_ + bwo3) = S.b3;                           \
        const float w0 = wcalc(S.a0.x, fsr, S.g0.x);                           \
        const float w1 = wcalc(S.a0.y, fsr, S.g0.y);                           \
        const float w2 = wcalc(S.a0.z, fsr, S.g0.z);                           \
        const float w3 = wcalc(S.a0.w, fsr, S.g0.w);                           \
        const float w4 = wcalc(S.a1.x, fsr, S.g1.x);                           \
        const float w5 = wcalc(S.a1.y, fsr, S.g1.y);                           \
        const float w6 = wcalc(S.a1.z, fsr, S.g1.z);                           \
        const float w7 = wcalc(S.a1.w, fsr, S.g1.w);                           \
        zacc += (w0 + w1) + (w2 + w3) + ((w4 + w5) + (w6 + w7));               \
        uint4 pk;                                                              \
        pk.x = pack_f16(w0, w1); pk.y = pack_f16(w2, w3);                      \
        pk.z = pack_f16(w4, w5); pk.w = pack_f16(w6, w7);                      \
        *reinterpret_cast<uint4*>(bs_ + awo) = pk;                             \
    }

#define MFMA_PHASE(BUF)                                                        \
    {                                                                          \
        const char* bb_ = smem + (BUF) * BUFB;                                 \
        __builtin_amdgcn_s_setprio(1);                                         \
        _Pragma("unroll")                                                      \
        for (int ks = 0; ks < 4; ++ks) {                                       \
            const int cb = (p * 128 + ks * 32 + kg8) * 2;                      \
            const f16x8 af = *reinterpret_cast<const f16x8*>(bb_ + aro + (cb ^ fswz)); \
            const f16x8 bv = *reinterpret_cast<const f16x8*>(bb_ + bro + (cb ^ fswz)); \
            acc = __builtin_amdgcn_mfma_f32_16x16x32_f16(af, bv, acc, 0, 0, 0);\
        }                                                                      \
        __builtin_amdgcn_s_setprio(0);                                         \
    }

    // prologue: tile0 -> buf0
    LOADG(0, RA);
    LOADG(1, RB);
    STAGE(RA, 0);
    LOADG(2, RA);
    BAR;

    for (int tt = 0; tt < NTILE; tt += 2) {
        // even iter: MFMA buf0 (tile tt); stage tile tt+1 -> buf1
        if (tt + 1 < NTILE) STAGE(RB, 1);
        if (tt + 3 < NTILE) LOADG(tt + 3, RB);
        MFMA_PHASE(0);
        BAR;
        // odd iter: MFMA buf1 (tile tt+1); stage tile tt+2 -> buf0
        if (tt + 2 < NTILE) STAGE(RA, 0);
        if (tt + 4 < NTILE) LOADG(tt + 4, RA);
        if (tt + 1 < NTILE) MFMA_PHASE(1);
        BAR;
    }
#undef LOADG
#undef STAGE
#undef MFMA_PHASE
#undef BAR

    // ---- Z reduction (each row's 32 threads share a wave half) ----
    float* zb = reinterpret_cast<float*>(smem + 8192);   // past acc region
    {
        float z = zacc;
#pragma unroll
        for (int off = 1; off < 32; off <<= 1) z += __shfl_xor(z, off, 64);
        if ((l & 31) == 0) zb[srow] = z;
    }

    // ---- cross-parity D reduction + epilogue (aliases tile LDS) ----
    *reinterpret_cast<f32x4*>(smem + w * 1024 + l * 16) = acc;
    __syncthreads();
#pragma unroll
    for (int e0 = 0; e0 < 2; ++e0) {
        const int e = t + e0 * 512;
        const int rr = e >> 6, f2 = e & 63;
        const int ft2 = f2 >> 4, n = f2 & 15;
        const int ln = n | ((rr >> 2) << 4);
        const int rg = rr & 3;
        const float s =
            *reinterpret_cast<const float*>(smem + ft2 * 1024 + ln * 16 + rg * 4) +
            *reinterpret_cast<const float*>(smem + (ft2 + 4) * 1024 + ln * 16 + rg * 4);
        const float hp = s / zb[rr];
        out[(size_t)(row0 + rr) * FOUT + f2] = hp > 0.f ? hp : expm1f(hp);
    }
}

extern "C" void kernel_launch(void* const* d_in, const int* in_sizes, int n_in,
                              void* d_out, int out_size, void* d_ws, size_t ws_size,
                              hipStream_t stream) {
    const float* h   = (const float*)d_in[0];
    const int*   adj = (const int*)d_in[1];
    const float* W   = (const float*)d_in[2];
    const float* a   = (const float*)d_in[3];
    float* out = (float*)d_out;

    float* ws = (float*)d_ws;
    float* fsrc = ws;
    float* fdst = fsrc + N;
    unsigned short* WhT = (unsigned short*)(fdst + N);   // FOUT*N f16 = 1 MB

    gat_prep<<<dim3(N / 16), dim3(256), 0, stream>>>(h, W, a, fsrc, fdst, WhT);
    gat_main<<<dim3(N / 16), dim3(512), 0, stream>>>(adj, WhT, fsrc, fdst, out);
}